// Round 7
// baseline (108.575 us; speedup 1.0000x reference)
//
#include <hip/hip_runtime.h>
#include <math.h>

#define NBOX 98            // 7*7*2
#define ROWLEN 1470        // floats per image
#define WLDSF 1472         // floats per wave LDS region = 368 float4 (16B multiple)
#define NMS_T 0.7f
#define SCORE_T 0.05f

// precise sigmoid — bit-matches the reference path (rare IoU-boundary recompute only)
__device__ __forceinline__ float psigm(float v) {
    return 1.0f / (1.0f + expf(-v));
}
// fast sigmoid: native exp + v_rcp_f32; box coords only (0.38 output tolerance)
__device__ __forceinline__ float fsigm(float v) {
    return __builtin_amdgcn_rcpf(1.0f + __expf(-v));
}

// async global->LDS, 16B/lane; LDS dest = wave-uniform base + lane*16
__device__ __forceinline__ void gl_lds16(const float4* g, float4* l) {
    __builtin_amdgcn_global_load_lds((const __attribute__((address_space(1))) void*)g,
                                     (__attribute__((address_space(3))) void*)l,
                                     16, 0, 0);
}

// Full per-image pipeline for one wave. row = LDS pointer to this image's 1470
// floats. Structural fact (any input): after decode+clamp, every box except the
// two anchors of cell (0,0) is degenerate (zero width or height) -> IoU==0 with
// everything -> greedy NMS reduces to one IoU check (box0 vs box1 of cell 0).
__device__ __forceinline__ void process(const float* __restrict__ row, int b, int lane,
                                        float* __restrict__ out, int batch) {
    const int  cell   = lane;
    const bool active = (cell < 49);

    float  s = 0.0f, lab = 0.0f;
    int    vbits = 0;
    float4 B0 = make_float4(1.f, 1.f, 1.f, 1.f);
    float4 B1 = make_float4(1.f, 1.f, 1.f, 1.f);

    if (active) {
        const float* c = row + cell * 30;
        float mx = c[10]; int ml = 0;                 // shared class argmax (first occurrence)
        #pragma unroll
        for (int t = 1; t < 20; ++t) {
            const float v = c[10 + t];
            if (v > mx) { mx = v; ml = t; }
        }
        s = mx; lab = (float)ml;

        const int ci = cell / 7;
        const int cj = cell - ci * 7;

        if (c[4] >= 0.0f) vbits |= 1;                 // sigmoid(o)>=0.5 <=> o>=0
        if (c[9] >= 0.0f) vbits |= 2;

        const float sx0 = fsigm(c[0]), sy0 = fsigm(c[1]);
        const float sw0 = fsigm(c[2]), sh0 = fsigm(c[3]);
        const float sx1 = fsigm(c[5]), sy1 = fsigm(c[6]);
        const float sw1 = fsigm(c[7]), sh1 = fsigm(c[8]);

        if (cj == 0) {                                // else exact 1.0 from clamp
            B0.x = fminf(fmaxf(sx0, 0.f), 1.f);
            B0.z = fminf(fmaxf(sx0 + sw0, 0.f), 1.f);
            B1.x = fminf(fmaxf(sx1, 0.f), 1.f);
            B1.z = fminf(fmaxf(sx1 + sw1, 0.f), 1.f);
        }
        if (ci == 0) {
            B0.y = fminf(fmaxf(sy0, 0.f), 1.f);
            B0.w = fminf(fmaxf(sy0 + sh0, 0.f), 1.f);
            B1.y = fminf(fmaxf(sy1, 0.f), 1.f);
            B1.w = fminf(fmaxf(sy1 + sh1, 0.f), 1.f);
        }
    }

    const bool v0 = (vbits & 1) != 0;
    const bool v1 = (vbits & 2) != 0;
    const int  cnt = (vbits & 1) + (vbits >> 1);

    const unsigned long long V0m = __ballot(v0);
    const unsigned long long V1m = __ballot(v1);
    const int V = (int)__popcll(V0m) + (int)__popcll(V1m);

    // the single possible suppression: box1 by box0 (cell 0)
    bool kill_local = false;
    if (cell == 0 && (vbits & 3) == 3) {
        const float a0 = (B0.z - B0.x) * (B0.w - B0.y);
        const float a1 = (B1.z - B1.x) * (B1.w - B1.y);
        const float w  = fmaxf(fminf(B0.z, B1.z) - fmaxf(B0.x, B1.x), 0.f);
        const float h  = fmaxf(fminf(B0.w, B1.w) - fmaxf(B0.y, B1.y), 0.f);
        const float inter = w * h;
        const float uni   = a0 + a1 - inter;
        const float delta = inter - NMS_T * uni;
        if (fabsf(delta) < 1e-4f * uni) {
            // fast-sigmoid error could flip the decision -> ref-exact recompute
            const float px0 = psigm(row[0]), py0 = psigm(row[1]);
            const float pw0 = psigm(row[2]), ph0 = psigm(row[3]);
            const float px1 = psigm(row[5]), py1 = psigm(row[6]);
            const float pw1 = psigm(row[7]), ph1 = psigm(row[8]);
            const float X0 = fminf(fmaxf(px0, 0.f), 1.f), Y0 = fminf(fmaxf(py0, 0.f), 1.f);
            const float Z0 = fminf(fmaxf(px0 + pw0, 0.f), 1.f), W0 = fminf(fmaxf(py0 + ph0, 0.f), 1.f);
            const float X1 = fminf(fmaxf(px1, 0.f), 1.f), Y1 = fminf(fmaxf(py1, 0.f), 1.f);
            const float Z1 = fminf(fmaxf(px1 + pw1, 0.f), 1.f), W1 = fminf(fmaxf(py1 + ph1, 0.f), 1.f);
            const float pa0 = (Z0 - X0) * (W0 - Y0);
            const float pa1 = (Z1 - X1) * (W1 - Y1);
            const float pw  = fmaxf(fminf(Z0, Z1) - fmaxf(X0, X1), 0.f);
            const float ph  = fmaxf(fminf(W0, W1) - fmaxf(Y0, Y1), 0.f);
            const float pint = pw * ph;
            const float puni = pa0 + pa1 - pint;
            const float iou  = (puni > 0.f) ? (pint / puni) : 0.f;
            kill_local = (iou > NMS_T);
        } else {
            kill_local = (delta > 0.f);
        }
    }
    const bool kill1 = (__ballot(kill_local) != 0ull);

    // packed key: (ord(score)<<8) | (63-cell)<<2 | cnt  — score desc, cell asc
    const int ib = __float_as_int(s);
    const unsigned uo = (unsigned)ib ^ (unsigned)((ib >> 31) | 0x80000000);
    const unsigned long long key =
        ((unsigned long long)uo << 8) | ((unsigned)(63 - cell) << 2) | (unsigned)cnt;
    const unsigned klo = (unsigned)key;
    const unsigned khi = (unsigned)(key >> 32);

    int acc0 = 0, acc1 = 0, acc2 = 0, acc3 = 0;
    #pragma unroll
    for (int j = 0; j < 49; ++j) {
        const unsigned jlo = (unsigned)__builtin_amdgcn_readlane((int)klo, j);
        const unsigned jhi = (unsigned)__builtin_amdgcn_readlane((int)khi, j);
        const unsigned long long kj = ((unsigned long long)jhi << 32) | jlo;
        const int cj_ = (int)(jlo & 3u);
        const int add = (kj > key) ? cj_ : 0;
        if ((j & 3) == 0) acc0 += add;
        else if ((j & 3) == 1) acc1 += add;
        else if ((j & 3) == 2) acc2 += add;
        else acc3 += add;
    }
    const int rcom = (acc0 + acc1) + (acc2 + acc3);

    const unsigned long long below = (1ull << cell) - 1ull;
    const int prefv = (int)__popcll(V0m & below) + (int)__popcll(V1m & below);

    const int r0 = v0 ? rcom : (V + 2 * cell - prefv);
    const int r1 = v1 ? (rcom + (v0 ? 1 : 0))
                      : (V + 2 * cell + 1 - prefv - (v0 ? 1 : 0));

    const bool k0 = v0 && (s >= SCORE_T);
    const bool k1 = v1 && (s >= SCORE_T) && !(kill1 && cell == 0);

    if (active) {
        float4* boxes = reinterpret_cast<float4*>(out + (size_t)b * (NBOX * 4));
        const size_t base1 = (size_t)batch * (NBOX * 4);
        const size_t bn    = (size_t)batch * NBOX;
        float* scores = out + base1 +          (size_t)b * NBOX;
        float* labels = out + base1 + bn +     (size_t)b * NBOX;
        float* keepm  = out + base1 + 2 * bn + (size_t)b * NBOX;

        const float4 z = make_float4(0.f, 0.f, 0.f, 0.f);
        boxes[r0]  = k0 ? B0 : z;
        boxes[r1]  = k1 ? B1 : z;
        scores[r0] = k0 ? s : 0.f;
        scores[r1] = k1 ? s : 0.f;
        labels[r0] = k0 ? lab : 0.f;
        labels[r1] = k1 ? lab : 0.f;
        keepm[r0]  = k0 ? 1.f : 0.f;
        keepm[r1]  = k1 ? 1.f : 0.f;
    }
}

// Persistent pipelined waves, ADJACENT image pairing (imgA=2gw, imgB=2gw+1):
// A staged via global_load_lds, B prefetched to VGPRs during A's compute, then
// ds_write'd into the same per-wave LDS region. No __syncthreads — waves fully
// decoupled. Adjacency keeps the wave's input reads and output writes in one
// contiguous window (R6's distant pairing tripled WRITE_SIZE via partial-line
// RMW; R2-R5 adjacency gave WRITE == exact output size).
__global__ __launch_bounds__(128) void yolo_post(const float* __restrict__ x,
                                                 float* __restrict__ out,
                                                 int batch) {
    const int wid  = threadIdx.x >> 6;
    const int lane = threadIdx.x & 63;
    const int gw   = blockIdx.x * 2 + wid;        // global wave id

    __shared__ __align__(16) float srow[2 * WLDSF];
    float* wbase = srow + wid * WLDSF;
    float4* ldst = reinterpret_cast<float4*>(wbase);
    const float4* gq = reinterpret_cast<const float4*>(x);
    const size_t totalQ = ((size_t)batch * ROWLEN) >> 2;

    const int imgA = 2 * gw;                      // element offset 2940*gw -> 16B aligned
    const int imgB = 2 * gw + 1;                  // element offset ... + 1470 -> rem 2

    const size_t qA = (size_t)gw * 735;           // 2940*gw / 4, exact
    const size_t qB = qA + 367;                   // floor((2940*gw + 1470)/4)

    // ---- stage A direct-to-LDS + prefetch B to VGPRs, back-to-back ----
    if (imgA < batch) {
        #pragma unroll
        for (int r = 0; r < 6; ++r) {
            const int slot = r * 64 + lane;
            if (slot < 368 && qA + (size_t)slot < totalQ)
                gl_lds16(gq + qA + slot, ldst + slot);
        }
    }
    float4 pf[6];
    if (imgB < batch) {
        #pragma unroll
        for (int r = 0; r < 6; ++r) {
            const int slot = r * 64 + lane;
            if (slot < 368 && qB + (size_t)slot < totalQ)
                pf[r] = gq[qB + slot];
        }
    }

    __builtin_amdgcn_s_waitcnt(0x0F70);   // vmcnt(0): A resident in LDS
    __builtin_amdgcn_wave_barrier();

    if (imgA < batch) process(wbase, imgA, lane, out, batch);   // remA == 0

    __builtin_amdgcn_s_waitcnt(0xC07F);   // lgkmcnt(0): drain A's ds_reads (WAR)
    __builtin_amdgcn_wave_barrier();

    if (imgB < batch) {
        #pragma unroll
        for (int r = 0; r < 6; ++r) {
            const int slot = r * 64 + lane;
            if (slot < 368 && qB + (size_t)slot < totalQ)
                ldst[slot] = pf[r];
        }
        __builtin_amdgcn_s_waitcnt(0xC07F);   // lgkmcnt(0): B writes visible
        __builtin_amdgcn_wave_barrier();
        process(wbase + 2, imgB, lane, out, batch);             // remB == 2
    }
}

extern "C" void kernel_launch(void* const* d_in, const int* in_sizes, int n_in,
                              void* d_out, int out_size, void* d_ws, size_t ws_size,
                              hipStream_t stream) {
    const float* x = (const float*)d_in[0];
    float* out = (float*)d_out;
    const int batch = in_sizes[0] / ROWLEN;   // 8192
    const int W     = (batch + 1) / 2;        // 4096 waves, 2 adjacent images each
    const int grid  = (W + 1) / 2;            // 2 waves per 128-thread block
    yolo_post<<<grid, 128, 0, stream>>>(x, out, batch);
}

// Round 8
// 99.680 us; speedup vs baseline: 1.0892x; 1.0892x over previous
//
#include <hip/hip_runtime.h>
#include <math.h>

#define NBOX 98            // 7*7*2
#define ROWLEN 1470        // floats per image
#define WLDSF 1472         // floats per wave LDS region = 368 float4 (16B multiple)
#define NMS_T 0.7f
#define SCORE_T 0.05f

// precise sigmoid — bit-matches the reference path (rare IoU-boundary recompute only)
__device__ __forceinline__ float psigm(float v) {
    return 1.0f / (1.0f + expf(-v));
}
// fast sigmoid: native exp + v_rcp_f32; box coords only (0.38 output tolerance)
__device__ __forceinline__ float fsigm(float v) {
    return __builtin_amdgcn_rcpf(1.0f + __expf(-v));
}

// async global->LDS, 16B/lane; LDS dest = wave-uniform base + lane*16
__device__ __forceinline__ void gl_lds16(const float4* g, float4* l) {
    __builtin_amdgcn_global_load_lds((const __attribute__((address_space(1))) void*)g,
                                     (__attribute__((address_space(3))) void*)l,
                                     16, 0, 0);
}

// Full per-image pipeline for one wave. row = LDS pointer to this image's 1470
// floats. Structural fact (any input): after decode+clamp, every box except the
// two anchors of cell (0,0) is degenerate (zero width or height) -> IoU==0 with
// everything -> greedy NMS reduces to one IoU check (box0 vs box1 of cell 0).
__device__ __forceinline__ void process(const float* __restrict__ row, int b, int lane,
                                        float* __restrict__ out, int batch) {
    const int  cell   = lane;
    const bool active = (cell < 49);

    float  s = 0.0f, lab = 0.0f;
    int    vbits = 0;
    float4 B0 = make_float4(1.f, 1.f, 1.f, 1.f);
    float4 B1 = make_float4(1.f, 1.f, 1.f, 1.f);

    if (active) {
        const float* c = row + cell * 30;
        float mx = c[10]; int ml = 0;                 // shared class argmax (first occurrence)
        #pragma unroll
        for (int t = 1; t < 20; ++t) {
            const float v = c[10 + t];
            if (v > mx) { mx = v; ml = t; }
        }
        s = mx; lab = (float)ml;

        const int ci = cell / 7;
        const int cj = cell - ci * 7;

        if (c[4] >= 0.0f) vbits |= 1;                 // sigmoid(o)>=0.5 <=> o>=0
        if (c[9] >= 0.0f) vbits |= 2;

        const float sx0 = fsigm(c[0]), sy0 = fsigm(c[1]);
        const float sw0 = fsigm(c[2]), sh0 = fsigm(c[3]);
        const float sx1 = fsigm(c[5]), sy1 = fsigm(c[6]);
        const float sw1 = fsigm(c[7]), sh1 = fsigm(c[8]);

        if (cj == 0) {                                // else exact 1.0 from clamp
            B0.x = fminf(fmaxf(sx0, 0.f), 1.f);
            B0.z = fminf(fmaxf(sx0 + sw0, 0.f), 1.f);
            B1.x = fminf(fmaxf(sx1, 0.f), 1.f);
            B1.z = fminf(fmaxf(sx1 + sw1, 0.f), 1.f);
        }
        if (ci == 0) {
            B0.y = fminf(fmaxf(sy0, 0.f), 1.f);
            B0.w = fminf(fmaxf(sy0 + sh0, 0.f), 1.f);
            B1.y = fminf(fmaxf(sy1, 0.f), 1.f);
            B1.w = fminf(fmaxf(sy1 + sh1, 0.f), 1.f);
        }
    }

    const bool v0 = (vbits & 1) != 0;
    const bool v1 = (vbits & 2) != 0;
    const int  cnt = (vbits & 1) + (vbits >> 1);

    const unsigned long long V0m = __ballot(v0);
    const unsigned long long V1m = __ballot(v1);
    const int V = (int)__popcll(V0m) + (int)__popcll(V1m);

    // the single possible suppression: box1 by box0 (cell 0)
    bool kill_local = false;
    if (cell == 0 && (vbits & 3) == 3) {
        const float a0 = (B0.z - B0.x) * (B0.w - B0.y);
        const float a1 = (B1.z - B1.x) * (B1.w - B1.y);
        const float w  = fmaxf(fminf(B0.z, B1.z) - fmaxf(B0.x, B1.x), 0.f);
        const float h  = fmaxf(fminf(B0.w, B1.w) - fmaxf(B0.y, B1.y), 0.f);
        const float inter = w * h;
        const float uni   = a0 + a1 - inter;
        const float delta = inter - NMS_T * uni;
        if (fabsf(delta) < 1e-4f * uni) {
            // fast-sigmoid error could flip the decision -> ref-exact recompute
            const float px0 = psigm(row[0]), py0 = psigm(row[1]);
            const float pw0 = psigm(row[2]), ph0 = psigm(row[3]);
            const float px1 = psigm(row[5]), py1 = psigm(row[6]);
            const float pw1 = psigm(row[7]), ph1 = psigm(row[8]);
            const float X0 = fminf(fmaxf(px0, 0.f), 1.f), Y0 = fminf(fmaxf(py0, 0.f), 1.f);
            const float Z0 = fminf(fmaxf(px0 + pw0, 0.f), 1.f), W0 = fminf(fmaxf(py0 + ph0, 0.f), 1.f);
            const float X1 = fminf(fmaxf(px1, 0.f), 1.f), Y1 = fminf(fmaxf(py1, 0.f), 1.f);
            const float Z1 = fminf(fmaxf(px1 + pw1, 0.f), 1.f), W1 = fminf(fmaxf(py1 + ph1, 0.f), 1.f);
            const float pa0 = (Z0 - X0) * (W0 - Y0);
            const float pa1 = (Z1 - X1) * (W1 - Y1);
            const float pw  = fmaxf(fminf(Z0, Z1) - fmaxf(X0, X1), 0.f);
            const float ph  = fmaxf(fminf(W0, W1) - fmaxf(Y0, Y1), 0.f);
            const float pint = pw * ph;
            const float puni = pa0 + pa1 - pint;
            const float iou  = (puni > 0.f) ? (pint / puni) : 0.f;
            kill_local = (iou > NMS_T);
        } else {
            kill_local = (delta > 0.f);
        }
    }
    const bool kill1 = (__ballot(kill_local) != 0ull);

    // packed key: (ord(score)<<8) | (63-cell)<<2 | cnt  — score desc, cell asc
    const int ib = __float_as_int(s);
    const unsigned uo = (unsigned)ib ^ (unsigned)((ib >> 31) | 0x80000000);
    const unsigned long long key =
        ((unsigned long long)uo << 8) | ((unsigned)(63 - cell) << 2) | (unsigned)cnt;
    const unsigned klo = (unsigned)key;
    const unsigned khi = (unsigned)(key >> 32);

    int acc0 = 0, acc1 = 0, acc2 = 0, acc3 = 0;
    #pragma unroll
    for (int j = 0; j < 49; ++j) {
        const unsigned jlo = (unsigned)__builtin_amdgcn_readlane((int)klo, j);
        const unsigned jhi = (unsigned)__builtin_amdgcn_readlane((int)khi, j);
        const unsigned long long kj = ((unsigned long long)jhi << 32) | jlo;
        const int cj_ = (int)(jlo & 3u);
        const int add = (kj > key) ? cj_ : 0;
        if ((j & 3) == 0) acc0 += add;
        else if ((j & 3) == 1) acc1 += add;
        else if ((j & 3) == 2) acc2 += add;
        else acc3 += add;
    }
    const int rcom = (acc0 + acc1) + (acc2 + acc3);

    const unsigned long long below = (1ull << cell) - 1ull;
    const int prefv = (int)__popcll(V0m & below) + (int)__popcll(V1m & below);

    const int r0 = v0 ? rcom : (V + 2 * cell - prefv);
    const int r1 = v1 ? (rcom + (v0 ? 1 : 0))
                      : (V + 2 * cell + 1 - prefv - (v0 ? 1 : 0));

    const bool k0 = v0 && (s >= SCORE_T);
    const bool k1 = v1 && (s >= SCORE_T) && !(kill1 && cell == 0);

    if (active) {
        float4* boxes = reinterpret_cast<float4*>(out + (size_t)b * (NBOX * 4));
        const size_t base1 = (size_t)batch * (NBOX * 4);
        const size_t bn    = (size_t)batch * NBOX;
        float* scores = out + base1 +          (size_t)b * NBOX;
        float* labels = out + base1 + bn +     (size_t)b * NBOX;
        float* keepm  = out + base1 + 2 * bn + (size_t)b * NBOX;

        const float4 z = make_float4(0.f, 0.f, 0.f, 0.f);
        boxes[r0]  = k0 ? B0 : z;
        boxes[r1]  = k1 ? B1 : z;
        scores[r0] = k0 ? s : 0.f;
        scores[r1] = k1 ? s : 0.f;
        labels[r0] = k0 ? lab : 0.f;
        labels[r1] = k1 ? lab : 0.f;
        keepm[r0]  = k0 ? 1.f : 0.f;
        keepm[r1]  = k1 ? 1.f : 0.f;
    }
}

// 2 fully-independent waves per 128-thread block; wave w owns image 2*bid+w.
// Each wave stages its own image via global_load_lds into its own LDS half,
// waits vmcnt(0) (per-wave), processes, exits. No __syncthreads anywhere —
// no inter-wave coupling (R5's block staging made waves wait on each other;
// R7's 2-images-per-wave halved occupancy). Adjacent images per block keep
// output boundary cache lines within one L2 (R6 lesson: distant pairing
// tripled WRITE_SIZE via partial-line RMW).
__global__ __launch_bounds__(128) void yolo_post(const float* __restrict__ x,
                                                 float* __restrict__ out,
                                                 int batch) {
    const int wid  = threadIdx.x >> 6;
    const int lane = threadIdx.x & 63;
    const int img  = blockIdx.x * 2 + wid;

    __shared__ __align__(16) float srow[2 * WLDSF];
    float*  wbase = srow + wid * WLDSF;
    float4* ldst  = reinterpret_cast<float4*>(wbase);
    const float4* gq = reinterpret_cast<const float4*>(x);
    const size_t totalQ = ((size_t)batch * ROWLEN) >> 2;

    if (img < batch) {
        // image base img*1470 floats: 16B-aligned for even img, 8B for odd.
        // Floor to the 16B quantum; rem = 2*(img&1) floats of lead-in.
        const size_t eoff = (size_t)img * ROWLEN;
        const int    rem  = (int)(eoff & 3);          // 0 or 2
        const size_t q0   = eoff >> 2;

        #pragma unroll
        for (int r = 0; r < 6; ++r) {
            const int slot = r * 64 + lane;
            if (slot < 368 && q0 + (size_t)slot < totalQ)
                gl_lds16(gq + q0 + slot, ldst + slot);
        }

        __builtin_amdgcn_s_waitcnt(0x0F70);   // vmcnt(0): image resident in LDS
        __builtin_amdgcn_wave_barrier();

        process(wbase + rem, img, lane, out, batch);
    }
}

extern "C" void kernel_launch(void* const* d_in, const int* in_sizes, int n_in,
                              void* d_out, int out_size, void* d_ws, size_t ws_size,
                              hipStream_t stream) {
    const float* x = (const float*)d_in[0];
    float* out = (float*)d_out;
    const int batch = in_sizes[0] / ROWLEN;   // 8192
    const int grid  = (batch + 1) / 2;        // 2 images per block, 1 per wave
    yolo_post<<<grid, 128, 0, stream>>>(x, out, batch);
}